// Round 16
// baseline (118.969 us; speedup 1.0000x reference)
//
#include <hip/hip_runtime.h>

typedef float f32x4 __attribute__((ext_vector_type(4)));
typedef unsigned short u16x8 __attribute__((ext_vector_type(8)));
typedef __bf16 bf16x8 __attribute__((ext_vector_type(8)));
typedef __bf16 bf16x4 __attribute__((ext_vector_type(4)));

// ---------------------------------------------------------------------------
// Kernel 1: convert + transpose three W (fp32 [256 k][512 n]) into bf16 W^T
// [role][512 n][256 k] in workspace, via 64x64 LDS tile transpose.
// ---------------------------------------------------------------------------
__global__ __launch_bounds__(256) void convert_w_kernel(
    const float* __restrict__ Wt_, const float* __restrict__ Wi_,
    const float* __restrict__ Wo_, unsigned short* __restrict__ out)
{
    __shared__ unsigned short tile[64][72];

    const int b    = blockIdx.x;
    const int role = b >> 5;
    const int kt   = (b & 31) >> 3;
    const int nt   = b & 7;
    const float* __restrict__ W = (role == 0) ? Wt_ : ((role == 1) ? Wi_ : Wo_);

    const int t  = threadIdx.x;
    const int r0 = t >> 4;
    const int c4 = (t & 15) << 2;

#pragma unroll
    for (int j = 0; j < 4; ++j) {
        const int kl = r0 + j * 16;
        f32x4 v = *(const f32x4*)(W + (size_t)(kt * 64 + kl) * 512 + nt * 64 + c4);
#pragma unroll
        for (int e = 0; e < 4; ++e)
            tile[c4 + e][kl] = __builtin_bit_cast(unsigned short, (__bf16)v[e]);
    }
    __syncthreads();

    const int cs = t & 7;
#pragma unroll
    for (int p = 0; p < 2; ++p) {
        const int r = (t >> 3) + p * 32;
        u16x8 v = *(const u16x8*)&tile[r][cs * 8];
        *(u16x8*)(out + (size_t)role * 512 * 256 +
                  (size_t)(nt * 64 + r) * 256 + kt * 64 + cs * 8) = v;
    }
}

// ---------------------------------------------------------------------------
// Kernel 2: EXACT R15 structure (114 us; 32 KB LDS with scratch reuse,
// 4 blocks/CU, single staging barrier + one raw lgkm-only barrier,
// full-density 1 KB load/store instructions, wave-private epilogue) with
// the LAST untested cache-policy cell: NT A loads + CACHED C stores.
// Rationale: R12 showed cached stores lose by evicting A from L3 -- but
// with NT A loads the read path never uses L3, while cached full-line
// stores gain L2 write-combining + async drain (the 7 TB/s fill's mode;
// NT stores showed 1.37x WRITE inflation and synchronous burst drains).
// ---------------------------------------------------------------------------
__global__ __launch_bounds__(512, 4) void role_proj_kernel(
    const float* __restrict__ A,            // [131072][256] fp32
    const int* __restrict__ tmask,          // [64]
    const int* __restrict__ imask,          // [64]
    const unsigned short* __restrict__ Wws, // [3][512][256] bf16 (W^T)
    const float* __restrict__ bt, const float* __restrict__ bi,
    const float* __restrict__ bo,
    float* __restrict__ C)                  // [131072][512] fp32
{
    // 32 KB: bf16 A tile (staging/compute), reused as epilogue scratch.
    __shared__ __align__(16) unsigned char smem[32 * 1024];
    unsigned short* As = (unsigned short*)smem;

    const int tid = threadIdx.x;
    const int m0  = blockIdx.x * 64;

    // role uniform per block: mask index = t/32 = blockIdx/32
    const int mi   = blockIdx.x >> 5;
    const int role = tmask[mi] ? 0 : (imask[mi] ? 1 : 2);
    const unsigned short* __restrict__ W = Wws + (size_t)role * (512 * 256);
    const float* __restrict__ bias = (role == 0) ? bt : ((role == 1) ? bi : bo);

    // ---- Phase 1: stage A (64 x 256 fp32 = 64 KB), full-density NT loads
    // (bypass L2/L3: read-once stream, leave caches to the store path).
    // Instruction p: 64 lanes x consecutive 16 B = 1 KB contiguous.
    const f32x4* abase = (const f32x4*)(A + (size_t)m0 * 256);
    f32x4 ld[8];
#pragma unroll
    for (int p = 0; p < 8; ++p)
        ld[p] = __builtin_nontemporal_load(abase + tid + 512 * p);
#pragma unroll
    for (int p = 0; p < 8; ++p) {
        const int u    = tid + 512 * p;       // float4-unit index in tile
        const int row  = u >> 6;              // 64 units per 256-float row
        const int slot = ((u & 63) >> 1) ^ (row & 7);   // 16 B slot, swizzled
        bf16x4 pk = { (__bf16)ld[p][0], (__bf16)ld[p][1],
                      (__bf16)ld[p][2], (__bf16)ld[p][3] };
        *(bf16x4*)(smem + row * 512 + slot * 16 + (u & 1) * 8) = pk;
    }
    __syncthreads();   // staging barrier (no outstanding stores)

    // ---- Phase 2: compute. Wave = 64 rows x 64 cols (wid strip).
    const int lane  = tid & 63;
    const int wid   = tid >> 6;
    const int l15   = lane & 15;
    const int l4    = lane >> 4;
    const int nbase = wid * 64;
    const int r7    = l15 & 7;

    const unsigned short* wp[4];
#pragma unroll
    for (int fn = 0; fn < 4; ++fn)
        wp[fn] = W + (size_t)(nbase + fn * 16 + l15) * 256 + l4 * 8;

    f32x4 acc[4][4] = {};          // [fm][fn]

#pragma unroll 1
    for (int ks = 0; ks < 8; ++ks) {
        u16x8 bfr[4];
#pragma unroll
        for (int fn = 0; fn < 4; ++fn)
            bfr[fn] = *(const u16x8*)(wp[fn] + ks * 32);   // L1/L2-resident
        u16x8 afr[4];
#pragma unroll
        for (int fm = 0; fm < 4; ++fm) {
            const int row  = fm * 16 + l15;
            const int slot = (ks * 4 + l4) ^ r7;
            afr[fm] = *(const u16x8*)&As[row * 256 + slot * 8];
        }
#pragma unroll
        for (int fm = 0; fm < 4; ++fm) {
#pragma unroll
            for (int fn = 0; fn < 4; ++fn) {
                // swapped operands: acc row = out-channel (4 consecutive per
                // lane via reg idx), col = activation row
                acc[fm][fn] = __builtin_amdgcn_mfma_f32_16x16x32_bf16(
                    __builtin_bit_cast(bf16x8, bfr[fn]),
                    __builtin_bit_cast(bf16x8, afr[fm]),
                    acc[fm][fn], 0, 0, 0);
            }
        }
    }

    // all waves done reading As; safe to reuse as scratch. Raw barrier:
    // lgkmcnt(0) only -- no VMEM drain (loads retired, stores not issued).
    __builtin_amdgcn_sched_barrier(0);
    asm volatile("s_waitcnt lgkmcnt(0)\n\ts_barrier" ::: "memory");
    __builtin_amdgcn_sched_barrier(0);

    // ---- Phase 3: wave-private epilogue in the dead A-tile, NO barriers.
    // Scratch: this wave's 4 KB = [16 act-rows][64 ch] fp32, 16 B-unit XOR
    // swizzle. Same-wave ds ordering guaranteed by data deps.
    unsigned char* cs = smem + wid * 4096;

    f32x4 bv[4];
#pragma unroll
    for (int fn = 0; fn < 4; ++fn)
        bv[fn] = *(const f32x4*)(bias + nbase + fn * 16 + l4 * 4);

#pragma unroll
    for (int fm = 0; fm < 4; ++fm) {
        // write acc slice: row = l15, 16B-unit g = fn*4+l4, swizzled by row
#pragma unroll
        for (int fn = 0; fn < 4; ++fn) {
            const int g = (fn * 4 + l4) ^ r7;
            *(f32x4*)(cs + l15 * 256 + g * 16) = acc[fm][fn] + bv[fn];
        }
        // read lane-linear + CACHED store: 4 rows x 256 B contiguous per
        // instruction (full lines -> no RFO; L2 drains asynchronously)
#pragma unroll
        for (int q = 0; q < 4; ++q) {
            const int r = (lane >> 4) + 4 * q;           // act-row 0..15
            const int g = (lane & 15) ^ (r & 7);         // swizzled 16B unit
            f32x4 v = *(const f32x4*)(cs + r * 256 + g * 16);
            *(f32x4*)(C + (size_t)(m0 + fm * 16 + r) * 512 +
                      nbase + (lane & 15) * 4) = v;
        }
    }
}

extern "C" void kernel_launch(void* const* d_in, const int* in_sizes, int n_in,
                              void* d_out, int out_size, void* d_ws, size_t ws_size,
                              hipStream_t stream) {
    const float* A   = (const float*)d_in[0];
    const int*   tm  = (const int*)d_in[1];
    const int*   im  = (const int*)d_in[2];
    const float* Wt_ = (const float*)d_in[3];
    const float* bt  = (const float*)d_in[4];
    const float* Wi_ = (const float*)d_in[5];
    const float* bi  = (const float*)d_in[6];
    const float* Wo_ = (const float*)d_in[7];
    const float* bo  = (const float*)d_in[8];

    unsigned short* Wws = (unsigned short*)d_ws;   // 3*512*256*2 = 768 KB

    hipLaunchKernelGGL(convert_w_kernel, dim3(96), dim3(256),
                       0, stream, Wt_, Wi_, Wo_, Wws);

    hipLaunchKernelGGL(role_proj_kernel, dim3(2048), dim3(512),
                       0, stream, A, tm, im, Wws, bt, bi, bo, (float*)d_out);
}

// Round 17
// 116.823 us; speedup vs baseline: 1.0184x; 1.0184x over previous
//
#include <hip/hip_runtime.h>

typedef float f32x4 __attribute__((ext_vector_type(4)));
typedef unsigned short u16x8 __attribute__((ext_vector_type(8)));
typedef __bf16 bf16x8 __attribute__((ext_vector_type(8)));

// ---------------------------------------------------------------------------
// Kernel 1: convert + transpose three W (fp32 [256 k][512 n]) into bf16 W^T
// [role][512 n][256 k] in workspace, via 64x64 LDS tile transpose.
// ---------------------------------------------------------------------------
__global__ __launch_bounds__(256) void convert_w_kernel(
    const float* __restrict__ Wt_, const float* __restrict__ Wi_,
    const float* __restrict__ Wo_, unsigned short* __restrict__ out)
{
    __shared__ unsigned short tile[64][72];

    const int b    = blockIdx.x;
    const int role = b >> 5;
    const int kt   = (b & 31) >> 3;
    const int nt   = b & 7;
    const float* __restrict__ W = (role == 0) ? Wt_ : ((role == 1) ? Wi_ : Wo_);

    const int t  = threadIdx.x;
    const int r0 = t >> 4;
    const int c4 = (t & 15) << 2;

#pragma unroll
    for (int j = 0; j < 4; ++j) {
        const int kl = r0 + j * 16;
        f32x4 v = *(const f32x4*)(W + (size_t)(kt * 64 + kl) * 512 + nt * 64 + c4);
#pragma unroll
        for (int e = 0; e < 4; ++e)
            tile[c4 + e][kl] = __builtin_bit_cast(unsigned short, (__bf16)v[e]);
    }
    __syncthreads();

    const int cs = t & 7;
#pragma unroll
    for (int p = 0; p < 2; ++p) {
        const int r = (t >> 3) + p * 32;
        u16x8 v = *(const u16x8*)&tile[r][cs * 8];
        *(u16x8*)(out + (size_t)role * 512 * 256 +
                  (size_t)(nt * 64 + r) * 256 + kt * 64 + cs * 8) = v;
    }
}

// ---------------------------------------------------------------------------
// Kernel 2: champion structure (R10/R15, 113 us) with the staging path
// replaced by global_load_lds DMA (the one untested canonical mechanism).
// A tile is fp32 [64 rows][1 KB] in LDS; each staging instruction DMAs one
// full 1 KB row (64 lanes x 16 B), with PRE-SWIZZLED per-lane global source
// (chunk = lane ^ (row&7)) so the linear LDS dest + XOR'd read side give
// conflict-free ds_read_b128 (rule #21 both-sides swizzle). No VGPR round
// trip, no staging VALU; fp32->bf16 conversion moves to the compute phase
// (VALU there is 5-7% busy). Epilogue unchanged: raw lgkm-only barrier,
// wave-private transpose scratch in the dead tile, NT full-line stores.
// ---------------------------------------------------------------------------
__global__ __launch_bounds__(512, 4) void role_proj_kernel(
    const float* __restrict__ A,            // [131072][256] fp32
    const int* __restrict__ tmask,          // [64]
    const int* __restrict__ imask,          // [64]
    const unsigned short* __restrict__ Wws, // [3][512][256] bf16 (W^T)
    const float* __restrict__ bt, const float* __restrict__ bi,
    const float* __restrict__ bo,
    float* __restrict__ C)                  // [131072][512] fp32
{
    // 64 KB: fp32 A tile (staging/compute); first 32 KB reused as scratch.
    __shared__ __align__(16) unsigned char smem[64 * 1024];

    const int tid  = threadIdx.x;
    const int lane = tid & 63;
    const int wid  = tid >> 6;
    const int m0   = blockIdx.x * 64;

    // role uniform per block: mask index = t/32 = blockIdx/32
    const int mi   = blockIdx.x >> 5;
    const int role = tmask[mi] ? 0 : (imask[mi] ? 1 : 2);
    const unsigned short* __restrict__ W = Wws + (size_t)role * (512 * 256);
    const float* __restrict__ bias = (role == 0) ? bt : ((role == 1) ? bi : bo);

    // ---- Phase 1: DMA-stage A (64 rows x 1 KB fp32) via global_load_lds.
    // Instruction j: wave-uniform LDS row base; per-lane global source is
    // the row's 16 B chunk (lane ^ j) -> LDS unit u holds chunk u ^ (row&7).
    // Full 1 KB contiguous coverage per instruction (permutation is within
    // 128 B lines' chunk order only at 16 B granularity -> full density).
#pragma unroll
    for (int j = 0; j < 8; ++j) {
        const int r = wid * 8 + j;            // row 0..63, r & 7 == j
        const float* gsrc = A + (size_t)(m0 + r) * 256 + ((lane ^ j) << 2);
        __builtin_amdgcn_global_load_lds(
            (const __attribute__((address_space(1))) unsigned int*)gsrc,
            (__attribute__((address_space(3))) unsigned int*)(smem + r * 1024),
            16, 0, 0);
    }
    __syncthreads();   // vmcnt(0) drain = DMA completion (required here)

    // ---- Phase 2: compute. Wave = 64 rows x 64 cols (wid strip).
    const int l15   = lane & 15;
    const int l4    = lane >> 4;
    const int nbase = wid * 64;
    const int r7    = l15 & 7;

    const unsigned short* wp[4];
#pragma unroll
    for (int fn = 0; fn < 4; ++fn)
        wp[fn] = W + (size_t)(nbase + fn * 16 + l15) * 256 + l4 * 8;

    f32x4 acc[4][4] = {};          // [fm][fn]

#pragma unroll 1
    for (int ks = 0; ks < 8; ++ks) {
        u16x8 bfr[4];
#pragma unroll
        for (int fn = 0; fn < 4; ++fn)
            bfr[fn] = *(const u16x8*)(wp[fn] + ks * 32);   // L1/L2-resident

        bf16x8 abf[4];
#pragma unroll
        for (int fm = 0; fm < 4; ++fm) {
            const int row = fm * 16 + l15;
            const int c0  = (ks * 8 + l4 * 2) ^ r7;        // swizzled units
            const int c1  = (ks * 8 + l4 * 2 + 1) ^ r7;
            f32x4 h0 = *(const f32x4*)(smem + row * 1024 + c0 * 16);
            f32x4 h1 = *(const f32x4*)(smem + row * 1024 + c1 * 16);
            bf16x8 a = { (__bf16)h0[0], (__bf16)h0[1],
                         (__bf16)h0[2], (__bf16)h0[3],
                         (__bf16)h1[0], (__bf16)h1[1],
                         (__bf16)h1[2], (__bf16)h1[3] };
            abf[fm] = a;
        }

#pragma unroll
        for (int fm = 0; fm < 4; ++fm) {
#pragma unroll
            for (int fn = 0; fn < 4; ++fn) {
                // swapped operands: acc row = out-channel (4 consecutive per
                // lane via reg idx), col = activation row
                acc[fm][fn] = __builtin_amdgcn_mfma_f32_16x16x32_bf16(
                    __builtin_bit_cast(bf16x8, bfr[fn]),
                    abf[fm],
                    acc[fm][fn], 0, 0, 0);
            }
        }
    }

    // all waves done reading the tile; safe to reuse as scratch. Raw
    // barrier: lgkmcnt(0) only -- no VMEM drain (DMA retired, stores not
    // yet issued).
    __builtin_amdgcn_sched_barrier(0);
    asm volatile("s_waitcnt lgkmcnt(0)\n\ts_barrier" ::: "memory");
    __builtin_amdgcn_sched_barrier(0);

    // ---- Phase 3: wave-private epilogue in the dead tile, NO barriers.
    // Scratch: this wave's 4 KB = [16 act-rows][64 ch] fp32, 16 B-unit XOR
    // swizzle. Same-wave ds ordering guaranteed by data deps.
    unsigned char* cs = smem + wid * 4096;

    f32x4 bv[4];
#pragma unroll
    for (int fn = 0; fn < 4; ++fn)
        bv[fn] = *(const f32x4*)(bias + nbase + fn * 16 + l4 * 4);

#pragma unroll
    for (int fm = 0; fm < 4; ++fm) {
        // write acc slice: row = l15, 16B-unit g = fn*4+l4, swizzled by row
#pragma unroll
        for (int fn = 0; fn < 4; ++fn) {
            const int g = (fn * 4 + l4) ^ r7;
            *(f32x4*)(cs + l15 * 256 + g * 16) = acc[fm][fn] + bv[fn];
        }
        // read lane-linear + NT store: 4 rows x 256 B contiguous per instr
#pragma unroll
        for (int q = 0; q < 4; ++q) {
            const int r = (lane >> 4) + 4 * q;           // act-row 0..15
            const int g = (lane & 15) ^ (r & 7);         // swizzled 16B unit
            f32x4 v = *(const f32x4*)(cs + r * 256 + g * 16);
            __builtin_nontemporal_store(
                v, (f32x4*)(C + (size_t)(m0 + fm * 16 + r) * 512 +
                            nbase + (lane & 15) * 4));
        }
    }
}

extern "C" void kernel_launch(void* const* d_in, const int* in_sizes, int n_in,
                              void* d_out, int out_size, void* d_ws, size_t ws_size,
                              hipStream_t stream) {
    const float* A   = (const float*)d_in[0];
    const int*   tm  = (const int*)d_in[1];
    const int*   im  = (const int*)d_in[2];
    const float* Wt_ = (const float*)d_in[3];
    const float* bt  = (const float*)d_in[4];
    const float* Wi_ = (const float*)d_in[5];
    const float* bi  = (const float*)d_in[6];
    const float* Wo_ = (const float*)d_in[7];
    const float* bo  = (const float*)d_in[8];

    unsigned short* Wws = (unsigned short*)d_ws;   // 3*512*256*2 = 768 KB

    hipLaunchKernelGGL(convert_w_kernel, dim3(96), dim3(256),
                       0, stream, Wt_, Wi_, Wo_, Wws);

    hipLaunchKernelGGL(role_proj_kernel, dim3(2048), dim3(512),
                       0, stream, A, tm, im, Wws, bt, bi, bo, (float*)d_out);
}